// Round 10
// baseline (145.470 us; speedup 1.0000x reference)
//
#include <hip/hip_runtime.h>
#include <math.h>

#define DD 2048
#define EE 64
#define KQ 32
#define TOKTILE 128

// ---------------- K1: gate GEMM, K-split partials ----------------
// R5 geometry (256 thr, 128 tok x 64 exp x 256 k, 4 tok x 8 exp/thread,
// 4 blocks/CU) but w comes from GLOBAL (L2-resident, vmcnt) into VGPRs per
// 4-k group instead of LDS -> DS pipe carries only the x reads (1 b128/k).
// fmaf k-chain ascending 0..kblk unchanged -> partial bitwise-identical.
__global__ __launch_bounds__(256, 4) void sr_gemm(
    const float* __restrict__ x, const float* __restrict__ wg,
    float* __restrict__ partial, int N, int ksplit)
{
  __shared__ float xs[KQ][TOKTILE];  // 16 KB, swizzled (t ^ 8*((k>>2)&3))
  const int ntiles = N / TOKTILE;
  const int tt = blockIdx.x % ntiles;
  const int kc = blockIdx.x / ntiles;
  const int kblk = DD / ksplit;
  const int nchunk = kblk / KQ;
  const int k0 = kc * kblk;
  const int t0 = tt * TOKTILE;
  const int tid = threadIdx.x;
  const int ti = tid & 31;   // token quad: tokens 4*ti .. 4*ti+3
  const int tj = tid >> 5;   // expert octet: experts 8*tj .. 8*tj+7

  float acc[4][8];
#pragma unroll
  for (int r = 0; r < 4; ++r)
#pragma unroll
    for (int c = 0; c < 8; ++c) acc[r][c] = 0.f;

  // x staging indices: 4 passes cover 128 rows x 32 k
  const int srowbase = tid >> 3;          // 0..31
  const int c4 = (tid & 7) * 4;           // k quad base
  const int swz = 8 * (tid & 3);          // == 8 * (((c4+j)>>2) & 3)

  for (int ch = 0; ch < nchunk; ++ch) {
    const int kb = k0 + ch * KQ;
#pragma unroll
    for (int p = 0; p < 4; ++p) {
      const int row = p * 32 + srowbase;
      const float4 v = *reinterpret_cast<const float4*>(
          &x[(size_t)(t0 + row) * DD + kb + c4]);
      const int srow = row ^ swz;         // 2-way bank spread on writes
      xs[c4 + 0][srow] = v.x;
      xs[c4 + 1][srow] = v.y;
      xs[c4 + 2][srow] = v.z;
      xs[c4 + 3][srow] = v.w;
    }
    __syncthreads();
#pragma unroll
    for (int sub = 0; sub < 8; ++sub) {
      // w[8tj+c][kb+4sub..+3] from global (L2): vmcnt path, no DS, no SMEM
      float4 wq[8];
#pragma unroll
      for (int c = 0; c < 8; ++c)
        wq[c] = *reinterpret_cast<const float4*>(
            &wg[(size_t)(8 * tj + c) * DD + kb + 4 * sub]);
      const int sk = 8 * (sub & 3);  // == 8*((k>>2)&3) for this group
#pragma unroll
      for (int kk = 0; kk < 4; ++kk) {
        const int k = 4 * sub + kk;
        float xv[4];
        *reinterpret_cast<float4*>(&xv[0]) =
            *reinterpret_cast<const float4*>(&xs[k][(4 * ti) ^ sk]);
#pragma unroll
        for (int r = 0; r < 4; ++r)
#pragma unroll
          for (int c = 0; c < 8; ++c)
            acc[r][c] = fmaf(xv[r], reinterpret_cast<const float*>(&wq[c])[kk],
                             acc[r][c]);
      }
    }
    __syncthreads();
  }
  // partial[kc][e][t]: float4 over tokens, coalesced
#pragma unroll
  for (int c = 0; c < 8; ++c) {
    const int e = 8 * tj + c;
    const float4 v = make_float4(acc[0][c], acc[1][c], acc[2][c], acc[3][c]);
    *reinterpret_cast<float4*>(&partial[((size_t)kc * EE + e) * N + t0 + 4 * ti]) = v;
  }
}

// ---------------- K2: cross-ksplit reduction -> logits[e][t] (+zero counts) ----
// f64 sum in fixed c-order: bitwise-identical to the passing path.
__global__ __launch_bounds__(256) void sr_reduce(
    const float* __restrict__ partial, float* __restrict__ logits,
    int* __restrict__ counts, int N, int ksplit)
{
  if (blockIdx.x == 0 && threadIdx.x < EE) counts[threadIdx.x] = 0;
  const int i4 = blockIdx.x * 256 + threadIdx.x;   // over EE*N/4
  const size_t base = (size_t)i4 * 4;
  if (base >= (size_t)EE * N) return;
  const size_t cs = (size_t)EE * N;
  double s0 = 0.0, s1 = 0.0, s2 = 0.0, s3 = 0.0;
  for (int c = 0; c < ksplit; ++c) {
    const float4 v = *reinterpret_cast<const float4*>(&partial[c * cs + base]);
    s0 += (double)v.x; s1 += (double)v.y; s2 += (double)v.z; s3 += (double)v.w;
  }
  *reinterpret_cast<float4*>(&logits[base]) =
      make_float4((float)s0, (float)s1, (float)s2, (float)s3);
}

// ---------------- K3: per-token softmax/argmax (128 tok / 256 thr blocks) ----
__global__ __launch_bounds__(256) void sr_softmax(
    const float* __restrict__ logits, float* __restrict__ dout,
    float* __restrict__ ws_w, int* __restrict__ ws_idx,
    int* __restrict__ counts, float* __restrict__ probsum, int N)
{
  __shared__ float lp[128][EE + 1];
  __shared__ float psq[4][EE];
  const int tid = threadIdx.x;
  const int t0 = blockIdx.x * 128;
  if (tid < 128) {
    const int t = t0 + tid;
    float l[EE];
    float maxv = -3.0e38f;
    int arg = 0;
#pragma unroll
    for (int e = 0; e < EE; ++e) {
      l[e] = logits[(size_t)e * N + t];
      if (l[e] > maxv) { maxv = l[e]; arg = e; }  // strict > : first max wins
    }
    float s = 0.f;
#pragma unroll
    for (int e = 0; e < EE; ++e) {
      const float ex = __expf(l[e] - maxv);
      lp[tid][e] = ex;
      s += ex;
    }
    const float inv = 1.0f / s;
    const float w = inv;  // exp(0)/sum
#pragma unroll
    for (int e = 0; e < EE; ++e) lp[tid][e] *= inv;
    dout[t] = w;
    dout[N + t] = (float)arg;
    ws_w[t] = w;
    ws_idx[t] = arg;
    atomicAdd(&counts[arg], 1);
  }
  __syncthreads();
  const int e = tid & 63, q = tid >> 6;
  float ps = 0.f;
  for (int r = 0; r < 32; ++r) ps += lp[q * 32 + r][e];
  psq[q][e] = ps;
  __syncthreads();
  if (tid < 64) {
    const float tot = ((psq[0][tid] + psq[1][tid]) + psq[2][tid]) + psq[3][tid];
    probsum[(size_t)blockIdx.x * EE + tid] = tot;
  }
}

// ---------------- K4: fused stats + select + apply (one 1024-thr block) ----
__device__ __forceinline__ int sr_bsum(int c, int red[][16], int pc, int tid) {
#pragma unroll
  for (int off = 32; off > 0; off >>= 1) c += __shfl_down(c, off, 64);
  if ((tid & 63) == 0) red[pc & 1][tid >> 6] = c;
  __syncthreads();
  int s = 0;
#pragma unroll
  for (int i = 0; i < 16; ++i) s += red[pc & 1][i];
  return s;
}

__global__ __launch_bounds__(1024) void sr_finish(
    const float* __restrict__ probsum, const int* __restrict__ counts,
    const float* __restrict__ ws_w, const int* __restrict__ ws_idx,
    float* __restrict__ dout, int N, int nblocks, int cap)
{
  __shared__ double dseg[16][EE];  // 8 KB
  __shared__ double mean_s[EE];
  __shared__ int cnt_s[EE];
  __shared__ int hdr[2];
  __shared__ int red[2][16];
  const int tid = threadIdx.x;
  const int PER = N / 1024;  // 16

  // load my tokens early; latency overlaps the stats phase
  float wv[16];
  int iv[16];
#pragma unroll
  for (int r = 0; r < 16; ++r) {
    float w = 0.f; int ix = -1;
    if (r < PER) {
      const int i = tid + r * 1024;
      w = ws_w[i];
      ix = ws_idx[i];
    }
    wv[r] = w; iv[r] = ix;
  }

  // ---- stats: mean gate probs, counts -> dout, aux loss, mode ----
  {
    const int e = tid & 63, seg = tid >> 6;
    const int per = nblocks / 16;
    double ps = 0.0;
    for (int b = seg * per; b < (seg + 1) * per; ++b)
      ps += (double)probsum[(size_t)b * EE + e];
    dseg[seg][e] = ps;
  }
  __syncthreads();
  if (tid < 64) {
    double tot = 0.0;
#pragma unroll
    for (int s2 = 0; s2 < 16; ++s2) tot += dseg[s2][tid];
    const int cnt = counts[tid];
    dout[2 * N + tid] = (float)cnt;
    mean_s[tid] = tot / (double)N;
    cnt_s[tid] = cnt;
  }
  __syncthreads();
  if (tid == 0) {
    double aux = 0.0;
    int nover = 0, e1 = -1;
    for (int i = 0; i < EE; ++i) {
      aux += ((double)cnt_s[i] / (double)N) * mean_s[i];
      if (cnt_s[i] > cap) { if (nover == 0) e1 = i; ++nover; }
    }
    dout[2 * N + EE] = (float)(aux * (double)EE);
    hdr[0] = (nover >= 2) ? 2 : nover;
    hdr[1] = e1;
  }
  __syncthreads();
  const int mode = hdr[0];

  if (mode == 0) return;  // softmax already wrote dout[t] = w
  if (mode == 2) {        // carried zeroing kills all weights
#pragma unroll
    for (int r = 0; r < 16; ++r)
      if (r < PER) dout[tid + r * 1024] = 0.f;
    return;
  }

  // ---- select: exact top-cap for over-capacity expert e1 ----
  const int e1 = hdr[1];
  unsigned mb[16];
#pragma unroll
  for (int r = 0; r < 16; ++r)
    mb[r] = (iv[r] == e1) ? __float_as_uint(wv[r]) : 0u;

  int pc = 0;
  // w = 1/softmax_sum in [1/64, 1): search bits in [0x3C000000, 0x3F800000)
  unsigned lo = 0x3C000000u, hi = 0x3F800000u;
  while (hi - lo > 1u) {
    const unsigned mid = lo + ((hi - lo) >> 1);
    int c = 0;
#pragma unroll
    for (int r = 0; r < 16; ++r) c += (mb[r] >= mid);
    const int tot = sr_bsum(c, red, pc++, tid);
    if (tot >= cap) lo = mid; else hi = mid;
  }
  int cge = 0, cgt = 0;
#pragma unroll
  for (int r = 0; r < 16; ++r) {
    cge += (mb[r] >= lo);
    cgt += (mb[r] > lo);
  }
  const int tot_ge = sr_bsum(cge, red, pc++, tid);
  const int tot_gt = sr_bsum(cgt, red, pc++, tid);
  const int quota = cap - tot_gt;
  int idx_thr = N - 1;
  if (tot_ge - tot_gt > quota) {
    // tie at tau: keep the quota lowest-index equals (lax.top_k tie-break)
    int l2 = -1, h2 = N - 1;
    while (h2 - l2 > 1) {
      const int mid = (l2 + h2) >> 1;
      int c = 0;
#pragma unroll
      for (int r = 0; r < 16; ++r) {
        const int i = tid + r * 1024;
        c += (mb[r] == lo && i <= mid) ? 1 : 0;
      }
      const int tot = sr_bsum(c, red, pc++, tid);
      if (tot >= quota) h2 = mid; else l2 = mid;
    }
    idx_thr = h2;
  }

  // ---- apply ----
#pragma unroll
  for (int r = 0; r < 16; ++r) {
    if (r < PER) {
      const int i = tid + r * 1024;
      const bool keep = (mb[r] > lo) || (mb[r] == lo && i <= idx_thr);
      dout[i] = keep ? wv[r] : 0.f;
    }
  }
}

// ---------------- launch ----------------
extern "C" void kernel_launch(void* const* d_in, const int* in_sizes, int n_in,
                              void* d_out, int out_size, void* d_ws, size_t ws_size,
                              hipStream_t stream)
{
  const float* x = (const float*)d_in[0];
  const float* wg = (const float*)d_in[1];
  const int N = in_sizes[0] / DD;  // 16384
  float* dout = (float*)d_out;
  float* wsf = (float*)d_ws;

  // ws layout (floats):
  // [ws_w N][ws_idx N][counts 64][probsum (N/128)*64][logits EE*N][partial ...]
  float* ws_w = wsf;
  int* ws_idx = (int*)(wsf + N);
  int* counts = (int*)(wsf + 2 * (size_t)N);
  float* probsum = wsf + 2 * (size_t)N + EE;
  const int nblocks_sm = N / 128;
  float* logits = wsf + 2 * (size_t)N + EE + (size_t)nblocks_sm * EE;
  float* partial = logits + (size_t)EE * N;
  const size_t base_floats = 2 * (size_t)N + EE + (size_t)nblocks_sm * EE + (size_t)EE * N;

  int ksplit = 8;
  while (ksplit > 1 &&
         (base_floats + (size_t)ksplit * EE * (size_t)N) * sizeof(float) > ws_size)
    ksplit >>= 1;
  const int cap = (int)((double)N * 1.25 / (double)EE);  // 320

  sr_gemm<<<(N / TOKTILE) * ksplit, 256, 0, stream>>>(x, wg, partial, N, ksplit);
  sr_reduce<<<(EE * N / 4 + 255) / 256, 256, 0, stream>>>(partial, logits, counts, N, ksplit);
  sr_softmax<<<N / 128, 256, 0, stream>>>(logits, dout, ws_w, ws_idx, counts, probsum, N);
  sr_finish<<<1, 1024, 0, stream>>>(probsum, counts, ws_w, ws_idx, dout, N, nblocks_sm, cap);
}

// Round 11
// 138.861 us; speedup vs baseline: 1.0476x; 1.0476x over previous
//
#include <hip/hip_runtime.h>
#include <math.h>

#define DD 2048
#define EE 64
#define KQ 32
#define TOKTILE 256

// ---------------- K1: gate GEMM, K-split partials ----------------
// R5's proven two-barrier structure, retiled: 256 thr, 256 tok x 64 exp x 256 k
// per block, thread tile 8 tok x 8 exp. Per thread-k: 2 x-b128 (32-addr,
// half-wave dup) + 2 w-b128 (broadcast) against 128 FMA cycles -> DS pipe no
// longer binding (R5 ratio was 3 b128 / 64 cyc -> 44% ceiling, measured 45%).
// fmaf chain ascending k over the same 256-k block -> partial bitwise-identical.
__global__ __launch_bounds__(256, 2) void sr_gemm(
    const float* __restrict__ x, const float* __restrict__ wg,
    float* __restrict__ partial, int N, int ksplit)
{
  __shared__ float xs[KQ][TOKTILE];  // 32 KB, swizzled (t ^ 8*((k>>2)&3))
  __shared__ float wsh[KQ][EE];      // 8 KB
  const int ntiles = N / TOKTILE;
  const int tt = blockIdx.x % ntiles;
  const int kc = blockIdx.x / ntiles;
  const int kblk = DD / ksplit;
  const int nchunk = kblk / KQ;
  const int k0 = kc * kblk;
  const int t0 = tt * TOKTILE;
  const int tid = threadIdx.x;
  const int ti = tid & 31;   // token quads: 4ti and 128+4ti
  const int tj = tid >> 5;   // expert octet: 8tj..8tj+7

  float acc[8][8];
#pragma unroll
  for (int r = 0; r < 8; ++r)
#pragma unroll
    for (int c = 0; c < 8; ++c) acc[r][c] = 0.f;

  // x staging: 8 passes x 32 rows; 8 thr/row, 128B contiguous
  const int srowbase = tid >> 3;          // 0..31
  const int c4 = (tid & 7) * 4;           // k quad base
  const int swz = 8 * (tid & 3);          // == 8 * (((c4+j)>>2) & 3)

  for (int ch = 0; ch < nchunk; ++ch) {
    const int kb = k0 + ch * KQ;
#pragma unroll
    for (int p = 0; p < 8; ++p) {
      const int row = p * 32 + srowbase;
      const float4 v = *reinterpret_cast<const float4*>(
          &x[(size_t)(t0 + row) * DD + kb + c4]);
      const int srow = row ^ swz;         // 2-way bank spread on writes
      xs[c4 + 0][srow] = v.x;
      xs[c4 + 1][srow] = v.y;
      xs[c4 + 2][srow] = v.z;
      xs[c4 + 3][srow] = v.w;
    }
    {
      const int e = tid >> 2;
      const int kq = (tid & 3) * 8;
      const float4 a = *reinterpret_cast<const float4*>(&wg[(size_t)e * DD + kb + kq]);
      const float4 b = *reinterpret_cast<const float4*>(&wg[(size_t)e * DD + kb + kq + 4]);
      wsh[kq + 0][e] = a.x; wsh[kq + 1][e] = a.y; wsh[kq + 2][e] = a.z; wsh[kq + 3][e] = a.w;
      wsh[kq + 4][e] = b.x; wsh[kq + 5][e] = b.y; wsh[kq + 6][e] = b.z; wsh[kq + 7][e] = b.w;
    }
    __syncthreads();
#pragma unroll 8
    for (int k = 0; k < KQ; ++k) {
      const int sk = 8 * ((k >> 2) & 3);
      float xv[8], wv[8];
      *reinterpret_cast<float4*>(&xv[0]) =
          *reinterpret_cast<const float4*>(&xs[k][(4 * ti) ^ sk]);
      *reinterpret_cast<float4*>(&xv[4]) =
          *reinterpret_cast<const float4*>(&xs[k][(128 + 4 * ti) ^ sk]);
      *reinterpret_cast<float4*>(&wv[0]) = *reinterpret_cast<const float4*>(&wsh[k][8 * tj]);
      *reinterpret_cast<float4*>(&wv[4]) = *reinterpret_cast<const float4*>(&wsh[k][8 * tj + 4]);
#pragma unroll
      for (int r = 0; r < 8; ++r)
#pragma unroll
        for (int c = 0; c < 8; ++c) acc[r][c] = fmaf(xv[r], wv[c], acc[r][c]);
    }
    __syncthreads();
  }
  // partial[kc][e][t]: float4 over tokens, coalesced
#pragma unroll
  for (int c = 0; c < 8; ++c) {
    const int e = 8 * tj + c;
#pragma unroll
    for (int h = 0; h < 2; ++h) {
      const float4 v = make_float4(acc[h * 4 + 0][c], acc[h * 4 + 1][c],
                                   acc[h * 4 + 2][c], acc[h * 4 + 3][c]);
      *reinterpret_cast<float4*>(
          &partial[((size_t)kc * EE + e) * N + t0 + h * 128 + 4 * ti]) = v;
    }
  }
}

// ---------------- K2: cross-ksplit reduction -> logits[e][t] (+zero counts) ----
// f64 sum in fixed c-order: bitwise-identical to the passing path.
__global__ __launch_bounds__(256) void sr_reduce(
    const float* __restrict__ partial, float* __restrict__ logits,
    int* __restrict__ counts, int N, int ksplit)
{
  if (blockIdx.x == 0 && threadIdx.x < EE) counts[threadIdx.x] = 0;
  const int i4 = blockIdx.x * 256 + threadIdx.x;   // over EE*N/4
  const size_t base = (size_t)i4 * 4;
  if (base >= (size_t)EE * N) return;
  const size_t cs = (size_t)EE * N;
  double s0 = 0.0, s1 = 0.0, s2 = 0.0, s3 = 0.0;
  for (int c = 0; c < ksplit; ++c) {
    const float4 v = *reinterpret_cast<const float4*>(&partial[c * cs + base]);
    s0 += (double)v.x; s1 += (double)v.y; s2 += (double)v.z; s3 += (double)v.w;
  }
  *reinterpret_cast<float4*>(&logits[base]) =
      make_float4((float)s0, (float)s1, (float)s2, (float)s3);
}

// ---------------- K3: per-token softmax/argmax (128 tok / 256 thr blocks) ----
__global__ __launch_bounds__(256) void sr_softmax(
    const float* __restrict__ logits, float* __restrict__ dout,
    float* __restrict__ ws_w, int* __restrict__ ws_idx,
    int* __restrict__ counts, float* __restrict__ probsum, int N)
{
  __shared__ float lp[128][EE + 1];
  __shared__ float psq[4][EE];
  const int tid = threadIdx.x;
  const int t0 = blockIdx.x * 128;
  if (tid < 128) {
    const int t = t0 + tid;
    float l[EE];
    float maxv = -3.0e38f;
    int arg = 0;
#pragma unroll
    for (int e = 0; e < EE; ++e) {
      l[e] = logits[(size_t)e * N + t];
      if (l[e] > maxv) { maxv = l[e]; arg = e; }  // strict > : first max wins
    }
    float s = 0.f;
#pragma unroll
    for (int e = 0; e < EE; ++e) {
      const float ex = __expf(l[e] - maxv);
      lp[tid][e] = ex;
      s += ex;
    }
    const float inv = 1.0f / s;
    const float w = inv;  // exp(0)/sum
#pragma unroll
    for (int e = 0; e < EE; ++e) lp[tid][e] *= inv;
    dout[t] = w;
    dout[N + t] = (float)arg;
    ws_w[t] = w;
    ws_idx[t] = arg;
    atomicAdd(&counts[arg], 1);
  }
  __syncthreads();
  const int e = tid & 63, q = tid >> 6;
  float ps = 0.f;
  for (int r = 0; r < 32; ++r) ps += lp[q * 32 + r][e];
  psq[q][e] = ps;
  __syncthreads();
  if (tid < 64) {
    const float tot = ((psq[0][tid] + psq[1][tid]) + psq[2][tid]) + psq[3][tid];
    probsum[(size_t)blockIdx.x * EE + tid] = tot;
  }
}

// ---------------- K4: fused stats + select + apply (one 1024-thr block) ----
__device__ __forceinline__ int sr_bsum(int c, int red[][16], int pc, int tid) {
#pragma unroll
  for (int off = 32; off > 0; off >>= 1) c += __shfl_down(c, off, 64);
  if ((tid & 63) == 0) red[pc & 1][tid >> 6] = c;
  __syncthreads();
  int s = 0;
#pragma unroll
  for (int i = 0; i < 16; ++i) s += red[pc & 1][i];
  return s;
}

__global__ __launch_bounds__(1024) void sr_finish(
    const float* __restrict__ probsum, const int* __restrict__ counts,
    const float* __restrict__ ws_w, const int* __restrict__ ws_idx,
    float* __restrict__ dout, int N, int nblocks, int cap)
{
  __shared__ double dseg[16][EE];  // 8 KB
  __shared__ double mean_s[EE];
  __shared__ int cnt_s[EE];
  __shared__ int hdr[2];
  __shared__ int red[2][16];
  const int tid = threadIdx.x;
  const int PER = N / 1024;  // 16

  // load my tokens early; latency overlaps the stats phase
  float wv[16];
  int iv[16];
#pragma unroll
  for (int r = 0; r < 16; ++r) {
    float w = 0.f; int ix = -1;
    if (r < PER) {
      const int i = tid + r * 1024;
      w = ws_w[i];
      ix = ws_idx[i];
    }
    wv[r] = w; iv[r] = ix;
  }

  // ---- stats: mean gate probs, counts -> dout, aux loss, mode ----
  {
    const int e = tid & 63, seg = tid >> 6;
    const int per = nblocks / 16;
    double ps = 0.0;
    for (int b = seg * per; b < (seg + 1) * per; ++b)
      ps += (double)probsum[(size_t)b * EE + e];
    dseg[seg][e] = ps;
  }
  __syncthreads();
  if (tid < 64) {
    double tot = 0.0;
#pragma unroll
    for (int s2 = 0; s2 < 16; ++s2) tot += dseg[s2][tid];
    const int cnt = counts[tid];
    dout[2 * N + tid] = (float)cnt;
    mean_s[tid] = tot / (double)N;
    cnt_s[tid] = cnt;
  }
  __syncthreads();
  if (tid == 0) {
    double aux = 0.0;
    int nover = 0, e1 = -1;
    for (int i = 0; i < EE; ++i) {
      aux += ((double)cnt_s[i] / (double)N) * mean_s[i];
      if (cnt_s[i] > cap) { if (nover == 0) e1 = i; ++nover; }
    }
    dout[2 * N + EE] = (float)(aux * (double)EE);
    hdr[0] = (nover >= 2) ? 2 : nover;
    hdr[1] = e1;
  }
  __syncthreads();
  const int mode = hdr[0];

  if (mode == 0) return;  // softmax already wrote dout[t] = w
  if (mode == 2) {        // carried zeroing kills all weights
#pragma unroll
    for (int r = 0; r < 16; ++r)
      if (r < PER) dout[tid + r * 1024] = 0.f;
    return;
  }

  // ---- select: exact top-cap for over-capacity expert e1 ----
  const int e1 = hdr[1];
  unsigned mb[16];
#pragma unroll
  for (int r = 0; r < 16; ++r)
    mb[r] = (iv[r] == e1) ? __float_as_uint(wv[r]) : 0u;

  int pc = 0;
  // w = 1/softmax_sum in [1/64, 1): search bits in [0x3C000000, 0x3F800000)
  unsigned lo = 0x3C000000u, hi = 0x3F800000u;
  while (hi - lo > 1u) {
    const unsigned mid = lo + ((hi - lo) >> 1);
    int c = 0;
#pragma unroll
    for (int r = 0; r < 16; ++r) c += (mb[r] >= mid);
    const int tot = sr_bsum(c, red, pc++, tid);
    if (tot >= cap) lo = mid; else hi = mid;
  }
  int cge = 0, cgt = 0;
#pragma unroll
  for (int r = 0; r < 16; ++r) {
    cge += (mb[r] >= lo);
    cgt += (mb[r] > lo);
  }
  const int tot_ge = sr_bsum(cge, red, pc++, tid);
  const int tot_gt = sr_bsum(cgt, red, pc++, tid);
  const int quota = cap - tot_gt;
  int idx_thr = N - 1;
  if (tot_ge - tot_gt > quota) {
    // tie at tau: keep the quota lowest-index equals (lax.top_k tie-break)
    int l2 = -1, h2 = N - 1;
    while (h2 - l2 > 1) {
      const int mid = (l2 + h2) >> 1;
      int c = 0;
#pragma unroll
      for (int r = 0; r < 16; ++r) {
        const int i = tid + r * 1024;
        c += (mb[r] == lo && i <= mid) ? 1 : 0;
      }
      const int tot = sr_bsum(c, red, pc++, tid);
      if (tot >= quota) h2 = mid; else l2 = mid;
    }
    idx_thr = h2;
  }

  // ---- apply ----
#pragma unroll
  for (int r = 0; r < 16; ++r) {
    if (r < PER) {
      const int i = tid + r * 1024;
      const bool keep = (mb[r] > lo) || (mb[r] == lo && i <= idx_thr);
      dout[i] = keep ? wv[r] : 0.f;
    }
  }
}

// ---------------- launch ----------------
extern "C" void kernel_launch(void* const* d_in, const int* in_sizes, int n_in,
                              void* d_out, int out_size, void* d_ws, size_t ws_size,
                              hipStream_t stream)
{
  const float* x = (const float*)d_in[0];
  const float* wg = (const float*)d_in[1];
  const int N = in_sizes[0] / DD;  // 16384
  float* dout = (float*)d_out;
  float* wsf = (float*)d_ws;

  // ws layout (floats):
  // [ws_w N][ws_idx N][counts 64][probsum (N/128)*64][logits EE*N][partial ...]
  float* ws_w = wsf;
  int* ws_idx = (int*)(wsf + N);
  int* counts = (int*)(wsf + 2 * (size_t)N);
  float* probsum = wsf + 2 * (size_t)N + EE;
  const int nblocks_sm = N / 128;
  float* logits = wsf + 2 * (size_t)N + EE + (size_t)nblocks_sm * EE;
  float* partial = logits + (size_t)EE * N;
  const size_t base_floats = 2 * (size_t)N + EE + (size_t)nblocks_sm * EE + (size_t)EE * N;

  int ksplit = 8;
  while (ksplit > 1 &&
         (base_floats + (size_t)ksplit * EE * (size_t)N) * sizeof(float) > ws_size)
    ksplit >>= 1;
  const int cap = (int)((double)N * 1.25 / (double)EE);  // 320

  sr_gemm<<<(N / TOKTILE) * ksplit, 256, 0, stream>>>(x, wg, partial, N, ksplit);
  sr_reduce<<<(EE * N / 4 + 255) / 256, 256, 0, stream>>>(partial, logits, counts, N, ksplit);
  sr_softmax<<<N / 128, 256, 0, stream>>>(logits, dout, ws_w, ws_idx, counts, probsum, N);
  sr_finish<<<1, 1024, 0, stream>>>(probsum, counts, ws_w, ws_idx, dout, N, nblocks_sm, cap);
}

// Round 13
// 132.976 us; speedup vs baseline: 1.0940x; 1.0443x over previous
//
#include <hip/hip_runtime.h>
#include <math.h>

#define DD 2048
#define EE 64
#define KQ 32
#define TOKTILE 128

// ---------------- K1: gate GEMM, K-split partials (R5/R9 verbatim, 80us) ----
// Tile: 128 tokens x 64 experts x 256 k per block. Thread tile 4 tok x 8 exp.
// xs is XOR-swizzled (t ^ 8*((k>>2)&3)); staging loads sit between the two
// barriers and are latency-hidden by 4 blocks/CU TLP. DO NOT restructure:
// SGPR-w (R6), reg-prefetch (R8), global-w (R10), 8x8@2blk (R11) all regressed.
__global__ __launch_bounds__(256, 4) void sr_gemm(
    const float* __restrict__ x, const float* __restrict__ wg,
    float* __restrict__ partial, int N, int ksplit)
{
  __shared__ float xs[KQ][TOKTILE];  // 16 KB, swizzled
  __shared__ float wsh[KQ][EE];      // 8 KB
  const int ntiles = N / TOKTILE;
  const int tt = blockIdx.x % ntiles;
  const int kc = blockIdx.x / ntiles;
  const int kblk = DD / ksplit;
  const int nchunk = kblk / KQ;
  const int k0 = kc * kblk;
  const int t0 = tt * TOKTILE;
  const int tid = threadIdx.x;
  const int ti = tid & 31;   // token quad: tokens 4*ti .. 4*ti+3
  const int tj = tid >> 5;   // expert octet: experts 8*tj .. 8*tj+7

  float acc[4][8];
#pragma unroll
  for (int r = 0; r < 4; ++r)
#pragma unroll
    for (int c = 0; c < 8; ++c) acc[r][c] = 0.f;

  // staging indices (x): 4 rounds cover 128 rows x 32 k
  const int srowbase = tid >> 3;          // 0..31
  const int c4 = (tid & 7) * 4;           // k quad base
  const int swz = 8 * (tid & 3);          // == 8 * (((c4+j)>>2) & 3)

  for (int ch = 0; ch < nchunk; ++ch) {
    const int kb = k0 + ch * KQ;
#pragma unroll
    for (int p = 0; p < 4; ++p) {
      const int row = p * 32 + srowbase;
      const float4 v = *reinterpret_cast<const float4*>(
          &x[(size_t)(t0 + row) * DD + kb + c4]);
      const int srow = row ^ swz;         // 2-way bank spread on writes
      xs[c4 + 0][srow] = v.x;
      xs[c4 + 1][srow] = v.y;
      xs[c4 + 2][srow] = v.z;
      xs[c4 + 3][srow] = v.w;
    }
    {
      const int e = tid >> 2;
      const int kq = (tid & 3) * 8;
      const float4 a = *reinterpret_cast<const float4*>(&wg[(size_t)e * DD + kb + kq]);
      const float4 b = *reinterpret_cast<const float4*>(&wg[(size_t)e * DD + kb + kq + 4]);
      wsh[kq + 0][e] = a.x; wsh[kq + 1][e] = a.y; wsh[kq + 2][e] = a.z; wsh[kq + 3][e] = a.w;
      wsh[kq + 4][e] = b.x; wsh[kq + 5][e] = b.y; wsh[kq + 6][e] = b.z; wsh[kq + 7][e] = b.w;
    }
    __syncthreads();
#pragma unroll 8
    for (int k = 0; k < KQ; ++k) {
      const int sk = 8 * ((k >> 2) & 3);
      float xv[4], wv[8];
      *reinterpret_cast<float4*>(&xv[0]) =
          *reinterpret_cast<const float4*>(&xs[k][(4 * ti) ^ sk]);
      *reinterpret_cast<float4*>(&wv[0]) = *reinterpret_cast<const float4*>(&wsh[k][8 * tj]);
      *reinterpret_cast<float4*>(&wv[4]) = *reinterpret_cast<const float4*>(&wsh[k][8 * tj + 4]);
#pragma unroll
      for (int r = 0; r < 4; ++r)
#pragma unroll
        for (int c = 0; c < 8; ++c) acc[r][c] = fmaf(xv[r], wv[c], acc[r][c]);
    }
    __syncthreads();
  }
  // partial[kc][e][t]: float4 over tokens, coalesced
#pragma unroll
  for (int c = 0; c < 8; ++c) {
    const int e = 8 * tj + c;
    const float4 v = make_float4(acc[0][c], acc[1][c], acc[2][c], acc[3][c]);
    *reinterpret_cast<float4*>(&partial[((size_t)kc * EE + e) * N + t0 + 4 * ti]) = v;
  }
}

// ---------------- K2: cross-ksplit reduction -> logits[e][t] (+zero counts) ----
// f64 sum in fixed c-order: bitwise-identical to the passing path.
__global__ __launch_bounds__(256) void sr_reduce(
    const float* __restrict__ partial, float* __restrict__ logits,
    int* __restrict__ counts, int N, int ksplit)
{
  if (blockIdx.x == 0 && threadIdx.x < EE) counts[threadIdx.x] = 0;
  const int i4 = blockIdx.x * 256 + threadIdx.x;   // over EE*N/4
  const size_t base = (size_t)i4 * 4;
  if (base >= (size_t)EE * N) return;
  const size_t cs = (size_t)EE * N;
  double s0 = 0.0, s1 = 0.0, s2 = 0.0, s3 = 0.0;
  for (int c = 0; c < ksplit; ++c) {
    const float4 v = *reinterpret_cast<const float4*>(&partial[c * cs + base]);
    s0 += (double)v.x; s1 += (double)v.y; s2 += (double)v.z; s3 += (double)v.w;
  }
  *reinterpret_cast<float4*>(&logits[base]) =
      make_float4((float)s0, (float)s1, (float)s2, (float)s3);
}

// ---------------- K3: per-token softmax/argmax (128 tok / 256 thr blocks) ----
__global__ __launch_bounds__(256) void sr_softmax(
    const float* __restrict__ logits, float* __restrict__ dout,
    float* __restrict__ ws_w, int* __restrict__ ws_idx,
    int* __restrict__ counts, float* __restrict__ probsum, int N)
{
  __shared__ float lp[128][EE + 1];
  __shared__ float psq[4][EE];
  const int tid = threadIdx.x;
  const int t0 = blockIdx.x * 128;
  if (tid < 128) {
    const int t = t0 + tid;
    float l[EE];
    float maxv = -3.0e38f;
    int arg = 0;
#pragma unroll
    for (int e = 0; e < EE; ++e) {
      l[e] = logits[(size_t)e * N + t];
      if (l[e] > maxv) { maxv = l[e]; arg = e; }  // strict > : first max wins
    }
    float s = 0.f;
#pragma unroll
    for (int e = 0; e < EE; ++e) {
      const float ex = __expf(l[e] - maxv);
      lp[tid][e] = ex;
      s += ex;
    }
    const float inv = 1.0f / s;
    const float w = inv;  // exp(0)/sum
#pragma unroll
    for (int e = 0; e < EE; ++e) lp[tid][e] *= inv;
    dout[t] = w;
    dout[N + t] = (float)arg;
    ws_w[t] = w;
    ws_idx[t] = arg;
    atomicAdd(&counts[arg], 1);
  }
  __syncthreads();
  const int e = tid & 63, q = tid >> 6;
  float ps = 0.f;
  for (int r = 0; r < 32; ++r) ps += lp[q * 32 + r][e];
  psq[q][e] = ps;
  __syncthreads();
  if (tid < 64) {
    const float tot = ((psq[0][tid] + psq[1][tid]) + psq[2][tid]) + psq[3][tid];
    probsum[(size_t)blockIdx.x * EE + tid] = tot;
  }
}

// ---------------- K4: fused stats + select + apply (one 1024-thr block) ----
__device__ __forceinline__ int sr_bsum(int c, int red[][16], int pc, int tid) {
#pragma unroll
  for (int off = 32; off > 0; off >>= 1) c += __shfl_down(c, off, 64);
  if ((tid & 63) == 0) red[pc & 1][tid >> 6] = c;
  __syncthreads();
  int s = 0;
#pragma unroll
  for (int i = 0; i < 16; ++i) s += red[pc & 1][i];
  return s;
}

__global__ __launch_bounds__(1024) void sr_finish(
    const float* __restrict__ probsum, const int* __restrict__ counts,
    const float* __restrict__ ws_w, const int* __restrict__ ws_idx,
    float* __restrict__ dout, int N, int nblocks, int cap)
{
  __shared__ double dseg[16][EE];  // 8 KB
  __shared__ double mean_s[EE];
  __shared__ int cnt_s[EE];
  __shared__ int hdr[2];
  __shared__ int red[2][16];
  const int tid = threadIdx.x;
  const int PER = N / 1024;  // 16

  // load my tokens early; latency overlaps the stats phase
  float wv[16];
  int iv[16];
#pragma unroll
  for (int r = 0; r < 16; ++r) {
    float w = 0.f; int ix = -1;
    if (r < PER) {
      const int i = tid + r * 1024;
      w = ws_w[i];
      ix = ws_idx[i];
    }
    wv[r] = w; iv[r] = ix;
  }

  // ---- stats: mean gate probs, counts -> dout, aux loss, mode ----
  {
    const int e = tid & 63, seg = tid >> 6;
    const int per = nblocks / 16;
    double ps = 0.0;
    for (int b = seg * per; b < (seg + 1) * per; ++b)
      ps += (double)probsum[(size_t)b * EE + e];
    dseg[seg][e] = ps;
  }
  __syncthreads();
  if (tid < 64) {
    double tot = 0.0;
#pragma unroll
    for (int s2 = 0; s2 < 16; ++s2) tot += dseg[s2][tid];
    const int cnt = counts[tid];
    dout[2 * N + tid] = (float)cnt;
    mean_s[tid] = tot / (double)N;
    cnt_s[tid] = cnt;
  }
  __syncthreads();
  if (tid == 0) {
    double aux = 0.0;
    int nover = 0, e1 = -1;
    for (int i = 0; i < EE; ++i) {
      aux += ((double)cnt_s[i] / (double)N) * mean_s[i];
      if (cnt_s[i] > cap) { if (nover == 0) e1 = i; ++nover; }
    }
    dout[2 * N + EE] = (float)(aux * (double)EE);
    hdr[0] = (nover >= 2) ? 2 : nover;
    hdr[1] = e1;
  }
  __syncthreads();
  const int mode = hdr[0];

  if (mode == 0) return;  // softmax already wrote dout[t] = w
  if (mode == 2) {        // carried zeroing kills all weights
#pragma unroll
    for (int r = 0; r < 16; ++r)
      if (r < PER) dout[tid + r * 1024] = 0.f;
    return;
  }

  // ---- select: exact top-cap for over-capacity expert e1 ----
  const int e1 = hdr[1];
  unsigned mb[16];
#pragma unroll
  for (int r = 0; r < 16; ++r)
    mb[r] = (iv[r] == e1) ? __float_as_uint(wv[r]) : 0u;

  int pc = 0;
  // w = 1/softmax_sum in [1/64, 1): search bits in [0x3C000000, 0x3F800000)
  unsigned lo = 0x3C000000u, hi = 0x3F800000u;
  while (hi - lo > 1u) {
    const unsigned mid = lo + ((hi - lo) >> 1);
    int c = 0;
#pragma unroll
    for (int r = 0; r < 16; ++r) c += (mb[r] >= mid);
    const int tot = sr_bsum(c, red, pc++, tid);
    if (tot >= cap) lo = mid; else hi = mid;
  }
  int cge = 0, cgt = 0;
#pragma unroll
  for (int r = 0; r < 16; ++r) {
    cge += (mb[r] >= lo);
    cgt += (mb[r] > lo);
  }
  const int tot_ge = sr_bsum(cge, red, pc++, tid);
  const int tot_gt = sr_bsum(cgt, red, pc++, tid);
  const int quota = cap - tot_gt;
  int idx_thr = N - 1;
  if (tot_ge - tot_gt > quota) {
    // tie at tau: keep the quota lowest-index equals (lax.top_k tie-break)
    int l2 = -1, h2 = N - 1;
    while (h2 - l2 > 1) {
      const int mid = (l2 + h2) >> 1;
      int c = 0;
#pragma unroll
      for (int r = 0; r < 16; ++r) {
        const int i = tid + r * 1024;
        c += (mb[r] == lo && i <= mid) ? 1 : 0;
      }
      const int tot = sr_bsum(c, red, pc++, tid);
      if (tot >= quota) h2 = mid; else l2 = mid;
    }
    idx_thr = h2;
  }

  // ---- apply ----
#pragma unroll
  for (int r = 0; r < 16; ++r) {
    if (r < PER) {
      const int i = tid + r * 1024;
      const bool keep = (mb[r] > lo) || (mb[r] == lo && i <= idx_thr);
      dout[i] = keep ? wv[r] : 0.f;
    }
  }
}

// ---------------- launch ----------------
extern "C" void kernel_launch(void* const* d_in, const int* in_sizes, int n_in,
                              void* d_out, int out_size, void* d_ws, size_t ws_size,
                              hipStream_t stream)
{
  const float* x = (const float*)d_in[0];
  const float* wg = (const float*)d_in[1];
  const int N = in_sizes[0] / DD;  // 16384
  float* dout = (float*)d_out;
  float* wsf = (float*)d_ws;

  // ws layout (floats):
  // [ws_w N][ws_idx N][counts 64][probsum (N/128)*64][logits EE*N][partial ...]
  float* ws_w = wsf;
  int* ws_idx = (int*)(wsf + N);
  int* counts = (int*)(wsf + 2 * (size_t)N);
  float* probsum = wsf + 2 * (size_t)N + EE;
  const int nblocks_sm = N / 128;
  float* logits = wsf + 2 * (size_t)N + EE + (size_t)nblocks_sm * EE;
  float* partial = logits + (size_t)EE * N;
  const size_t base_floats = 2 * (size_t)N + EE + (size_t)nblocks_sm * EE + (size_t)EE * N;

  int ksplit = 8;
  while (ksplit > 1 &&
         (base_floats + (size_t)ksplit * EE * (size_t)N) * sizeof(float) > ws_size)
    ksplit >>= 1;
  const int cap = (int)((double)N * 1.25 / (double)EE);  // 320

  sr_gemm<<<(N / TOKTILE) * ksplit, 256, 0, stream>>>(x, wg, partial, N, ksplit);
  sr_reduce<<<(EE * N / 4 + 255) / 256, 256, 0, stream>>>(partial, logits, counts, N, ksplit);
  sr_softmax<<<N / 128, 256, 0, stream>>>(logits, dout, ws_w, ws_idx, counts, probsum, N);
  sr_finish<<<1, 1024, 0, stream>>>(probsum, counts, ws_w, ws_idx, dout, N, nblocks_sm, cap);
}

// Round 17
// 128.649 us; speedup vs baseline: 1.1308x; 1.0336x over previous
//
#include <hip/hip_runtime.h>
#include <math.h>

#define DD 2048
#define EE 64
#define KQ 32
#define TOKTILE 128
#define KSPLIT 8

// ---------------- K1: gate GEMM, K-split partials ----------------
// Two-barrier structure (proven R5/R9/R13), retiled for DS-pipe relief:
// 128 thr (2 waves), tile 128 tok x 64 exp x 256 k, thread tile 8 tok x 8 exp.
// Per wave-k: 2 x-b128 + 2 w-b128 against 64 FMA-instr -> VALU ceiling ~67%
// (was 3 b128 / 32 FMA -> 44%, measured 45% for 3 rounds). Grid 1024 = 4
// blocks/CU (launch_bounds(128,2)): 4 independent barrier groups per CU so
// 3 blocks compute while 1 stages. Each output's fmaf chain is the same
// ascending-k sequence -> partial bitwise-identical -> absmax 0.0 preserved.
__global__ __launch_bounds__(128, 2) void sr_gemm(
    const float* __restrict__ x, const float* __restrict__ wg,
    float* __restrict__ partial, int N)
{
  __shared__ float xs[KQ][TOKTILE];  // 16 KB, swizzled (t ^ 8*((k>>2)&3))
  __shared__ float wsh[KQ][EE];      // 8 KB
  const int ntiles = N / TOKTILE;    // 128
  const int tt = blockIdx.x % ntiles;
  const int kc = blockIdx.x / ntiles;
  const int kblk = DD / KSPLIT;      // 256
  const int nchunk = kblk / KQ;      // 8
  const int k0 = kc * kblk;
  const int t0 = tt * TOKTILE;
  const int tid = threadIdx.x;
  const int ti = tid & 15;   // token octet: tokens 8*ti .. 8*ti+7
  const int tj = tid >> 4;   // expert octet: experts 8*tj .. 8*tj+7

  float acc[8][8];
#pragma unroll
  for (int r = 0; r < 8; ++r)
#pragma unroll
    for (int c = 0; c < 8; ++c) acc[r][c] = 0.f;

  // x staging: 8 passes x 16 rows; 8 thr/row, 128B contiguous per row
  const int srowb = tid >> 3;             // 0..15
  const int c4 = (tid & 7) * 4;           // k quad base
  const int swz = 8 * (tid & 3);          // == 8 * (((c4+j)>>2) & 3)
  // w staging: 2 thr/expert row, 16 consecutive k each
  const int we = tid >> 1;
  const int wk = (tid & 1) * 16;

  for (int ch = 0; ch < nchunk; ++ch) {
    const int kb = k0 + ch * KQ;
#pragma unroll
    for (int p = 0; p < 8; ++p) {
      const int row = p * 16 + srowb;
      const float4 v = *reinterpret_cast<const float4*>(
          &x[(size_t)(t0 + row) * DD + kb + c4]);
      const int srow = row ^ swz;         // 2-way bank spread on writes
      xs[c4 + 0][srow] = v.x;
      xs[c4 + 1][srow] = v.y;
      xs[c4 + 2][srow] = v.z;
      xs[c4 + 3][srow] = v.w;
    }
#pragma unroll
    for (int q = 0; q < 4; ++q) {
      const float4 a = *reinterpret_cast<const float4*>(
          &wg[(size_t)we * DD + kb + wk + 4 * q]);
      wsh[wk + 4 * q + 0][we] = a.x;
      wsh[wk + 4 * q + 1][we] = a.y;
      wsh[wk + 4 * q + 2][we] = a.z;
      wsh[wk + 4 * q + 3][we] = a.w;
    }
    __syncthreads();
#pragma unroll 8
    for (int k = 0; k < KQ; ++k) {
      const int sk = 8 * ((k >> 2) & 3);
      float xv[8], wv[8];
      // tokens 8ti..8ti+7: (8ti+j)^sk == (8ti^sk)+j since sk only has bits 3-4
      const int xb = (8 * ti) ^ sk;
      *reinterpret_cast<float4*>(&xv[0]) =
          *reinterpret_cast<const float4*>(&xs[k][xb]);
      *reinterpret_cast<float4*>(&xv[4]) =
          *reinterpret_cast<const float4*>(&xs[k][xb + 4]);
      *reinterpret_cast<float4*>(&wv[0]) =
          *reinterpret_cast<const float4*>(&wsh[k][8 * tj]);
      *reinterpret_cast<float4*>(&wv[4]) =
          *reinterpret_cast<const float4*>(&wsh[k][8 * tj + 4]);
#pragma unroll
      for (int r = 0; r < 8; ++r)
#pragma unroll
        for (int c = 0; c < 8; ++c) acc[r][c] = fmaf(xv[r], wv[c], acc[r][c]);
    }
    __syncthreads();
  }
  // partial[kc][e][t]: two float4s per (c): tokens 8ti..+3, 8ti+4..+7
#pragma unroll
  for (int c = 0; c < 8; ++c) {
    const int e = 8 * tj + c;
    const size_t base = ((size_t)kc * EE + e) * N + t0 + 8 * ti;
    *reinterpret_cast<float4*>(&partial[base]) =
        make_float4(acc[0][c], acc[1][c], acc[2][c], acc[3][c]);
    *reinterpret_cast<float4*>(&partial[base + 4]) =
        make_float4(acc[4][c], acc[5][c], acc[6][c], acc[7][c]);
  }
}

// ---------------- K2: cross-ksplit reduction -> logits[e][t] (+zero counts) ----
// f64 sum in fixed c-order (compile-time unrolled -> pipelined loads):
// bitwise-identical to the passing path.
__global__ __launch_bounds__(256) void sr_reduce(
    const float* __restrict__ partial, float* __restrict__ logits,
    int* __restrict__ counts, int N)
{
  if (blockIdx.x == 0 && threadIdx.x < EE) counts[threadIdx.x] = 0;
  const int i4 = blockIdx.x * 256 + threadIdx.x;   // over EE*N/4
  const size_t base = (size_t)i4 * 4;
  if (base >= (size_t)EE * N) return;
  const size_t cs = (size_t)EE * N;
  double s0 = 0.0, s1 = 0.0, s2 = 0.0, s3 = 0.0;
#pragma unroll
  for (int c = 0; c < KSPLIT; ++c) {
    const float4 v = *reinterpret_cast<const float4*>(&partial[c * cs + base]);
    s0 += (double)v.x; s1 += (double)v.y; s2 += (double)v.z; s3 += (double)v.w;
  }
  *reinterpret_cast<float4*>(&logits[base]) =
      make_float4((float)s0, (float)s1, (float)s2, (float)s3);
}

// ---------------- K3: per-token softmax/argmax (128 tok / 256 thr blocks) ----
__global__ __launch_bounds__(256) void sr_softmax(
    const float* __restrict__ logits, float* __restrict__ dout,
    float* __restrict__ ws_w, int* __restrict__ ws_idx,
    int* __restrict__ counts, float* __restrict__ probsum, int N)
{
  __shared__ float lp[128][EE + 1];
  __shared__ float psq[4][EE];
  const int tid = threadIdx.x;
  const int t0 = blockIdx.x * 128;
  if (tid < 128) {
    const int t = t0 + tid;
    float l[EE];
    float maxv = -3.0e38f;
    int arg = 0;
#pragma unroll
    for (int e = 0; e < EE; ++e) {
      l[e] = logits[(size_t)e * N + t];
      if (l[e] > maxv) { maxv = l[e]; arg = e; }  // strict > : first max wins
    }
    float s = 0.f;
#pragma unroll
    for (int e = 0; e < EE; ++e) {
      const float ex = __expf(l[e] - maxv);
      lp[tid][e] = ex;
      s += ex;
    }
    const float inv = 1.0f / s;
    const float w = inv;  // exp(0)/sum
#pragma unroll
    for (int e = 0; e < EE; ++e) lp[tid][e] *= inv;
    dout[t] = w;
    dout[N + t] = (float)arg;
    ws_w[t] = w;
    ws_idx[t] = arg;
    atomicAdd(&counts[arg], 1);
  }
  __syncthreads();
  const int e = tid & 63, q = tid >> 6;
  float ps = 0.f;
  for (int r = 0; r < 32; ++r) ps += lp[q * 32 + r][e];
  psq[q][e] = ps;
  __syncthreads();
  if (tid < 64) {
    const float tot = ((psq[0][tid] + psq[1][tid]) + psq[2][tid]) + psq[3][tid];
    probsum[(size_t)blockIdx.x * EE + tid] = tot;
  }
}

// ---------------- K4: fused stats + select + apply (one 1024-thr block) ----
__device__ __forceinline__ int sr_bsum(int c, int red[][16], int pc, int tid) {
#pragma unroll
  for (int off = 32; off > 0; off >>= 1) c += __shfl_down(c, off, 64);
  if ((tid & 63) == 0) red[pc & 1][tid >> 6] = c;
  __syncthreads();
  int s = 0;
#pragma unroll
  for (int i = 0; i < 16; ++i) s += red[pc & 1][i];
  return s;
}

__global__ __launch_bounds__(1024) void sr_finish(
    const float* __restrict__ probsum, const int* __restrict__ counts,
    const float* __restrict__ ws_w, const int* __restrict__ ws_idx,
    float* __restrict__ dout, int N, int nblocks, int cap)
{
  __shared__ double dseg[16][EE];  // 8 KB
  __shared__ double mean_s[EE];
  __shared__ int cnt_s[EE];
  __shared__ int hdr[2];
  __shared__ int red[2][16];
  const int tid = threadIdx.x;
  const int PER = N / 1024;  // 16

  // load my tokens early; latency overlaps the stats phase
  float wv[16];
  int iv[16];
#pragma unroll
  for (int r = 0; r < 16; ++r) {
    float w = 0.f; int ix = -1;
    if (r < PER) {
      const int i = tid + r * 1024;
      w = ws_w[i];
      ix = ws_idx[i];
    }
    wv[r] = w; iv[r] = ix;
  }

  // ---- stats: mean gate probs, counts -> dout, aux loss, mode ----
  {
    const int e = tid & 63, seg = tid >> 6;
    const int per = nblocks / 16;
    double ps = 0.0;
    for (int b = seg * per; b < (seg + 1) * per; ++b)
      ps += (double)probsum[(size_t)b * EE + e];
    dseg[seg][e] = ps;
  }
  __syncthreads();
  if (tid < 64) {
    double tot = 0.0;
#pragma unroll
    for (int s2 = 0; s2 < 16; ++s2) tot += dseg[s2][tid];
    const int cnt = counts[tid];
    dout[2 * N + tid] = (float)cnt;
    mean_s[tid] = tot / (double)N;
    cnt_s[tid] = cnt;
  }
  __syncthreads();
  if (tid == 0) {
    double aux = 0.0;
    int nover = 0, e1 = -1;
    for (int i = 0; i < EE; ++i) {
      aux += ((double)cnt_s[i] / (double)N) * mean_s[i];
      if (cnt_s[i] > cap) { if (nover == 0) e1 = i; ++nover; }
    }
    dout[2 * N + EE] = (float)(aux * (double)EE);
    hdr[0] = (nover >= 2) ? 2 : nover;
    hdr[1] = e1;
  }
  __syncthreads();
  const int mode = hdr[0];

  if (mode == 0) return;  // softmax already wrote dout[t] = w
  if (mode == 2) {        // carried zeroing kills all weights
#pragma unroll
    for (int r = 0; r < 16; ++r)
      if (r < PER) dout[tid + r * 1024] = 0.f;
    return;
  }

  // ---- select: exact top-cap for over-capacity expert e1 ----
  const int e1 = hdr[1];
  unsigned mb[16];
#pragma unroll
  for (int r = 0; r < 16; ++r)
    mb[r] = (iv[r] == e1) ? __float_as_uint(wv[r]) : 0u;

  int pc = 0;
  // w = 1/softmax_sum in [1/64, 1): search bits in [0x3C000000, 0x3F800000)
  unsigned lo = 0x3C000000u, hi = 0x3F800000u;
  while (hi - lo > 1u) {
    const unsigned mid = lo + ((hi - lo) >> 1);
    int c = 0;
#pragma unroll
    for (int r = 0; r < 16; ++r) c += (mb[r] >= mid);
    const int tot = sr_bsum(c, red, pc++, tid);
    if (tot >= cap) lo = mid; else hi = mid;
  }
  int cge = 0, cgt = 0;
#pragma unroll
  for (int r = 0; r < 16; ++r) {
    cge += (mb[r] >= lo);
    cgt += (mb[r] > lo);
  }
  const int tot_ge = sr_bsum(cge, red, pc++, tid);
  const int tot_gt = sr_bsum(cgt, red, pc++, tid);
  const int quota = cap - tot_gt;
  int idx_thr = N - 1;
  if (tot_ge - tot_gt > quota) {
    // tie at tau: keep the quota lowest-index equals (lax.top_k tie-break)
    int l2 = -1, h2 = N - 1;
    while (h2 - l2 > 1) {
      const int mid = (l2 + h2) >> 1;
      int c = 0;
#pragma unroll
      for (int r = 0; r < 16; ++r) {
        const int i = tid + r * 1024;
        c += (mb[r] == lo && i <= mid) ? 1 : 0;
      }
      const int tot = sr_bsum(c, red, pc++, tid);
      if (tot >= quota) h2 = mid; else l2 = mid;
    }
    idx_thr = h2;
  }

  // ---- apply ----
#pragma unroll
  for (int r = 0; r < 16; ++r) {
    if (r < PER) {
      const int i = tid + r * 1024;
      const bool keep = (mb[r] > lo) || (mb[r] == lo && i <= idx_thr);
      dout[i] = keep ? wv[r] : 0.f;
    }
  }
}

// ---------------- launch ----------------
extern "C" void kernel_launch(void* const* d_in, const int* in_sizes, int n_in,
                              void* d_out, int out_size, void* d_ws, size_t ws_size,
                              hipStream_t stream)
{
  const float* x = (const float*)d_in[0];
  const float* wg = (const float*)d_in[1];
  const int N = in_sizes[0] / DD;  // 16384
  float* dout = (float*)d_out;
  float* wsf = (float*)d_ws;

  // ws layout (floats):
  // [ws_w N][ws_idx N][counts 64][probsum (N/128)*64][logits EE*N][partial ...]
  float* ws_w = wsf;
  int* ws_idx = (int*)(wsf + N);
  int* counts = (int*)(wsf + 2 * (size_t)N);
  float* probsum = wsf + 2 * (size_t)N + EE;
  const int nblocks_sm = N / 128;
  float* logits = wsf + 2 * (size_t)N + EE + (size_t)nblocks_sm * EE;
  float* partial = logits + (size_t)EE * N;
  const int cap = (int)((double)N * 1.25 / (double)EE);  // 320

  sr_gemm<<<(N / TOKTILE) * KSPLIT, 128, 0, stream>>>(x, wg, partial, N);
  sr_reduce<<<(EE * N / 4 + 255) / 256, 256, 0, stream>>>(partial, logits, counts, N);
  sr_softmax<<<N / 128, 256, 0, stream>>>(logits, dout, ws_w, ws_idx, counts, probsum, N);
  sr_finish<<<1, 1024, 0, stream>>>(probsum, counts, ws_w, ws_idx, dout, N, nblocks_sm, cap);
}